// Round 18
// baseline (264.551 us; speedup 1.0000x reference)
//
#include <hip/hip_runtime.h>

#define AS1 __attribute__((address_space(1)))
#define AS3 __attribute__((address_space(3)))

typedef __bf16 bf16x8 __attribute__((ext_vector_type(8)));
typedef float f32x4 __attribute__((ext_vector_type(4)));
typedef float f32x16 __attribute__((ext_vector_type(16)));
typedef unsigned short us8 __attribute__((ext_vector_type(8)));
typedef unsigned int u32x4 __attribute__((ext_vector_type(4)));

static constexpr int T_ = 2048;
static constexpr int NH_ = 16;
static constexpr int NKV_ = 4;
static constexpr int HD_ = 128;
static constexpr int NQKV_ = 5120;   // 4096 (q|gate interleaved per head) + 512 k + 512 v
// 1/sqrt(128) * log2(e): softmax computed in exp2 domain
static constexpr float SL2E_ = 0.12751744f;

static __device__ __forceinline__ unsigned short f2b(float f) {
  unsigned u = __builtin_bit_cast(unsigned, f);
  u += 0x7fffu + ((u >> 16) & 1u);
  return (unsigned short)(u >> 16);
}
static __device__ __forceinline__ float b2f(unsigned short h) {
  unsigned u = ((unsigned)h) << 16;
  return __builtin_bit_cast(float, u);
}
static __device__ __forceinline__ void load_lds16(const void* g, void* l) {
  __builtin_amdgcn_global_load_lds((const AS1 unsigned int*)g, (AS3 unsigned int*)l, 16, 0, 0);
}
static __device__ __forceinline__ f32x4 mfma16(bf16x8 a, bf16x8 b, f32x4 c) {
  return __builtin_amdgcn_mfma_f32_16x16x32_bf16(a, b, c, 0, 0, 0);
}
static __device__ __forceinline__ f32x16 mfma32(bf16x8 a, bf16x8 b, f32x16 c) {
  return __builtin_amdgcn_mfma_f32_32x32x16_bf16(a, b, c, 0, 0, 0);
}
static __device__ __forceinline__ unsigned cvtpk(float lo, float hi) {
  unsigned r;
  asm("v_cvt_pk_bf16_f32 %0, %1, %2" : "=v"(r) : "v"(lo), "v"(hi));
  return r;
}
static __device__ __forceinline__ void pl32swap(unsigned& a, unsigned& b) {
  asm("v_permlane32_swap_b32 %0, %1" : "+v"(a), "+v"(b));
}
#define S_BARRIER() asm volatile("s_barrier" ::: "memory")
#define VMCNT(n) asm volatile("s_waitcnt vmcnt(" #n ")" ::: "memory")

// ---------------------------------------------------------------- conversions
__global__ __launch_bounds__(256) void conv_bf16_kernel(
    const float* __restrict__ src, unsigned short* __restrict__ dst, int n) {
  int i = (blockIdx.x * 256 + threadIdx.x) * 4;
  if (i >= n) return;
  float4 v = *(const float4*)(src + i);
  ushort4 o;
  o.x = f2b(v.x); o.y = f2b(v.y); o.z = f2b(v.z); o.w = f2b(v.w);
  *(ushort4*)(dst + i) = o;
}

// transpose-convert with vectorized stores: src f32 (R x C) row-major ->
// dst bf16 rows [roff+c0 .. ) x R. 32x32 tile; loads coalesced f32; each thread
// stores one ushort4 (8B/lane vs 2B/lane scalar).
static __device__ __forceinline__ void tconv_tile(
    const float* __restrict__ src, unsigned short* __restrict__ dst,
    int R, int C, int roff, int c0, int r0) {
  __shared__ float tile[32][33];
  const int tx = threadIdx.x & 31, ty = threadIdx.x >> 5;   // 32 x 8
#pragma unroll
  for (int j = 0; j < 32; j += 8)
    tile[ty + j][tx] = src[(size_t)(r0 + ty + j) * C + c0 + tx];
  __syncthreads();
  const int orow = threadIdx.x >> 3;          // 0..31: output row (= src col)
  const int oc4 = (threadIdx.x & 7) * 4;      // 0..28: first of 4 output cols (= src rows)
  ushort4 o;
  o.x = f2b(tile[oc4 + 0][orow]);
  o.y = f2b(tile[oc4 + 1][orow]);
  o.z = f2b(tile[oc4 + 2][orow]);
  o.w = f2b(tile[oc4 + 3][orow]);
  *(ushort4*)&dst[(size_t)(roff + c0 + orow) * R + r0 + oc4] = o;
}

// fused QKV weight transpose: one launch covers all 5120 output rows.
// global col gc0 selects source: [0,4096) wq, [4096,4608) wk, [4608,5120) wv.
__global__ __launch_bounds__(256) void tconv_qkv_kernel(
    const float* __restrict__ wq, const float* __restrict__ wk,
    const float* __restrict__ wv, unsigned short* __restrict__ dst) {
  const int gc0 = blockIdx.x * 32, r0 = blockIdx.y * 32;
  const float* src;
  int C, c0;
  if (gc0 < 4096)      { src = wq; C = 4096; c0 = gc0; }
  else if (gc0 < 4608) { src = wk; C = 512;  c0 = gc0 - 4096; }
  else                 { src = wv; C = 512;  c0 = gc0 - 4608; }
  // dst row = gc0 + local col; write with roff folded into gc0-c0
  tconv_tile(src, dst, 2048, C, gc0 - c0, c0, r0);
}

__global__ __launch_bounds__(256) void tconv_kernel(
    const float* __restrict__ src, unsigned short* __restrict__ dst, int R, int C) {
  tconv_tile(src, dst, R, C, 0, blockIdx.x * 32, blockIdx.y * 32);
}

// ---------------------------------------------------------------- GEMM (R3-verified structure)
// A (M x K) bf16, Bt (N x K) bf16, C (M x N).  BM=128 BN=256 BK=64, 8 waves (2Mx4N),
// triple-buffered LDS, prefetch distance 2, counted vmcnt(6), XOR slot-swizzle.
// BF16OUT=1 (QKV gemm): blocks with bcol>=4608 write V transposed straight to Vt.
template <int BF16OUT>
__global__ __launch_bounds__(512, 2) void gemm_bt8_kernel(
    const unsigned short* __restrict__ A, const unsigned short* __restrict__ Bt,
    void* __restrict__ Cv, unsigned short* __restrict__ Vt, int K, int N) {
  __shared__ __align__(16) unsigned short As[3][128 * 64];
  __shared__ __align__(16) unsigned short Bs[3][256 * 64];
  const int tid = threadIdx.x;
  const int wid = tid >> 6, lane = tid & 63;
  const int lq = lane & 15, lg = lane >> 4;
  const int l8 = lane >> 3, s8 = lane & 7;
  const int wr = wid >> 2, wc = wid & 3;          // 2 x 4 wave grid
  const int brow = blockIdx.y * 128, bcol = blockIdx.x * 256;

  f32x4 acc[4][4];
#pragma unroll
  for (int m = 0; m < 4; ++m)
#pragma unroll
    for (int n = 0; n < 4; ++n) acc[m][n] = (f32x4){0.f, 0.f, 0.f, 0.f};

  auto STAGE_HALF = [&](int t, int b3t, int half) {
    const int k0 = t * 64;
    {
      const int ca = wid + half * 8;
      const int row = ca * 8 + l8;
      load_lds16(A + (size_t)(brow + row) * K + k0 + ((s8 ^ (row & 7)) << 3),
                 &As[b3t][ca << 9]);
    }
#pragma unroll
    for (int j = 0; j < 2; ++j) {
      const int cb = wid + half * 16 + (j << 3);
      const int row = cb * 8 + l8;
      load_lds16(Bt + (size_t)(bcol + row) * K + k0 + ((s8 ^ (row & 7)) << 3),
                 &Bs[b3t][cb << 9]);
    }
  };
  auto PHASE_READS = [&](int b3, int ks, bf16x8* a, bf16x8* bb) {
#pragma unroll
    for (int m = 0; m < 4; ++m) {
      const int r = wr * 64 + m * 16 + lq;
      a[m] = *(const bf16x8*)&As[b3][r * 64 + (((ks * 4 + lg) ^ (r & 7)) << 3)];
    }
#pragma unroll
    for (int n = 0; n < 4; ++n) {
      const int r = wc * 64 + n * 16 + lq;
      bb[n] = *(const bf16x8*)&Bs[b3][r * 64 + (((ks * 4 + lg) ^ (r & 7)) << 3)];
    }
  };
  auto DO_MFMA = [&](bf16x8* a, bf16x8* bb) {
    __builtin_amdgcn_s_setprio(1);
#pragma unroll
    for (int m = 0; m < 4; ++m)
#pragma unroll
      for (int n = 0; n < 4; ++n) acc[m][n] = mfma16(a[m], bb[n], acc[m][n]);
    __builtin_amdgcn_s_setprio(0);
  };

  STAGE_HALF(0, 0, 0); STAGE_HALF(0, 0, 1);
  STAGE_HALF(1, 1, 0); STAGE_HALF(1, 1, 1);
  VMCNT(6);
  S_BARRIER();

  int b3 = 0;
  for (int t = 0; t < 32; ++t) {
    const int b3p2 = b3 < 1 ? b3 + 2 : b3 - 1;
    bf16x8 a[4], bb[4];
    PHASE_READS(b3, 0, a, bb);
    if (t < 30) STAGE_HALF(t + 2, b3p2, 0);
    S_BARRIER();
    __builtin_amdgcn_sched_barrier(0);
    DO_MFMA(a, bb);
    S_BARRIER();
    PHASE_READS(b3, 1, a, bb);
    if (t < 30) STAGE_HALF(t + 2, b3p2, 1);
    if (t < 30) {
      VMCNT(6);
    } else if (t == 30) {
      VMCNT(0);
    }
    S_BARRIER();
    __builtin_amdgcn_sched_barrier(0);
    DO_MFMA(a, bb);
    if (t < 31) S_BARRIER();
    b3 = b3 < 2 ? b3 + 1 : 0;
  }
  if constexpr (BF16OUT) {
    if (bcol >= 4608) {
      // V columns: write transposed to Vt (B,NKV,HD,T), contiguous in t per lane
#pragma unroll
      for (int m = 0; m < 4; ++m) {
        const int R0 = brow + wr * 64 + m * 16 + lg * 4;   // = b*2048 + t0 (t0 % 4 == 0)
        const int bb2 = R0 >> 11, tt0 = R0 & 2047;
#pragma unroll
        for (int n = 0; n < 4; ++n) {
          const int vcol = bcol + wc * 64 + n * 16 + lq - 4608;   // 0..511
          const int vh = vcol >> 7, d = vcol & 127;
          ushort4 v4;
          v4.x = f2b(acc[m][n][0]); v4.y = f2b(acc[m][n][1]);
          v4.z = f2b(acc[m][n][2]); v4.w = f2b(acc[m][n][3]);
          *(ushort4*)&Vt[(size_t)((bb2 * 4 + vh) * 128 + d) * 2048 + tt0] = v4;
        }
      }
      return;
    }
  }
#pragma unroll
  for (int m = 0; m < 4; ++m)
#pragma unroll
    for (int n = 0; n < 4; ++n)
#pragma unroll
      for (int r = 0; r < 4; ++r) {
        const size_t idx =
            (size_t)(brow + wr * 64 + m * 16 + lg * 4 + r) * N + bcol + wc * 64 + n * 16 + lq;
        if constexpr (BF16OUT) {
          ((unsigned short*)Cv)[idx] = f2b(acc[m][n][r]);
        } else {
          ((float*)Cv)[idx] = acc[m][n][r];
        }
      }
}

// ---------------------------------------------------------------- rmsnorm + rope + layout
__global__ __launch_bounds__(256) void postproc_kernel(
    const unsigned short* __restrict__ qkv, const float* __restrict__ cosT,
    const float* __restrict__ sinT, const float* __restrict__ qnw,
    const float* __restrict__ knw, unsigned short* __restrict__ Qg,
    unsigned short* __restrict__ Kg) {
  const int row = blockIdx.x;                 // b*T + t
  const int b = row >> 11, t = row & 2047;
  const unsigned short* src = qkv + (size_t)row * NQKV_;
  const int tid = threadIdx.x;
  const int sub = tid & 15;
  const int i0 = sub * 8;
  const bool lo = sub < 8;

  float cs[8], sn[8];
#pragma unroll
  for (int j = 0; j < 8; ++j) {
    cs[j] = cosT[(size_t)row * HD_ + i0 + j];
    sn[j] = sinT[(size_t)row * HD_ + i0 + j];
  }
  {
    const int h = tid >> 4;
    us8 qv = *(const us8*)(src + h * 256 + i0);
    float q[8], ss = 0.f;
#pragma unroll
    for (int j = 0; j < 8; ++j) { q[j] = b2f(qv[j]); ss += q[j] * q[j]; }
    ss += __shfl_xor(ss, 1); ss += __shfl_xor(ss, 2);
    ss += __shfl_xor(ss, 4); ss += __shfl_xor(ss, 8);
    const float rms = rsqrtf(ss * (1.f / 128.f) + 1e-6f);
    float qn[8];
#pragma unroll
    for (int j = 0; j < 8; ++j) qn[j] = q[j] * rms * qnw[i0 + j];
    float pr[8];
#pragma unroll
    for (int j = 0; j < 8; ++j) pr[j] = __shfl_xor(qn[j], 8);
    us8 ov;
#pragma unroll
    for (int j = 0; j < 8; ++j) ov[j] = f2b(qn[j] * cs[j] + (lo ? -pr[j] : pr[j]) * sn[j]);
    *(us8*)(Qg + ((size_t)(b * NH_ + h) * T_ + t) * HD_ + i0) = ov;
  }
  if (tid < 64) {
    const int kh = tid >> 4;
    us8 kv8 = *(const us8*)(src + 4096 + kh * 128 + i0);
    float k[8], ss = 0.f;
#pragma unroll
    for (int j = 0; j < 8; ++j) { k[j] = b2f(kv8[j]); ss += k[j] * k[j]; }
    ss += __shfl_xor(ss, 1); ss += __shfl_xor(ss, 2);
    ss += __shfl_xor(ss, 4); ss += __shfl_xor(ss, 8);
    const float rms = rsqrtf(ss * (1.f / 128.f) + 1e-6f);
    float kn[8];
#pragma unroll
    for (int j = 0; j < 8; ++j) kn[j] = k[j] * rms * knw[i0 + j];
    float pr[8];
#pragma unroll
    for (int j = 0; j < 8; ++j) pr[j] = __shfl_xor(kn[j], 8);
    us8 ov;
#pragma unroll
    for (int j = 0; j < 8; ++j) ov[j] = f2b(kn[j] * cs[j] + (lo ? -pr[j] : pr[j]) * sn[j]);
    *(us8*)(Kg + ((size_t)(b * NKV_ + kh) * T_ + t) * HD_ + i0) = ov;
  }
}

// ---------------------------------------------------------------- flash attention
// R2-VERIFIED sync structure (passed 13 rounds incl. graph replays). Do NOT convert to
// raw s_barrier + counted vmcnt without a dedicated race screen (R7 diverged).
// T13 defer-max (wave-uniform VALU-only branch, no sync change).
__global__ __launch_bounds__(256, 2) void attn_kernel(
    const unsigned short* __restrict__ Qg, const unsigned short* __restrict__ Kg,
    const unsigned short* __restrict__ Vt, const unsigned short* __restrict__ qkv,
    unsigned short* __restrict__ attnb) {
  __shared__ __align__(16) char smem[65536];  // [2][ K 16KB | V 16KB ]
  const int i = blockIdx.x;
  const int xi = (i >> 3) & 15;                    // q-tile slot within group
  const int grp = (i & 7) + ((i >> 7) << 3);       // 0..31 = h + 16*b
  const int h = grp & 15, b = grp >> 4;
  const int qt = b ? (15 - xi) : xi;               // heavy+light pairing across b
  const int kh = h >> 2;
  const int tid = threadIdx.x, wid = tid >> 6, lane = tid & 63;
  const int lq = lane & 31, hi = lane >> 5;
  const int q0 = qt * 128;
  const int qbase = q0 + wid * 32;                 // wave's 32 q-rows
  const int qrow = qbase + lq;                     // this lane's q-row

  bf16x8 qf[8];
  const unsigned short* qptr = Qg + ((size_t)(b * NH_ + h) * T_ + qrow) * HD_;
#pragma unroll
  for (int t = 0; t < 8; ++t) qf[t] = *(const bf16x8*)(qptr + t * 16 + hi * 8);

  const char* Kbase = (const char*)(Kg + (size_t)(b * NKV_ + kh) * T_ * HD_);
  const char* Vbase = (const char*)(Vt + (size_t)(b * NKV_ + kh) * HD_ * T_);

  f32x16 o[4];
#pragma unroll
  for (int d = 0; d < 4; ++d)
#pragma unroll
    for (int r = 0; r < 16; ++r) o[d][r] = 0.f;
  float m_r = -1e30f, l_r = 0.f;
  const int nt = 2 * qt + 2;

  auto STAGE = [&](int tt, int c) {
    const int t0 = tt * 64;
    char* kd = smem + c * 32768;
    char* vd = kd + 16384;
#pragma unroll
    for (int j = 0; j < 4; ++j) {
      const int ch = j * 4 + wid;
      const int kv = ch * 4 + (lane >> 4);
      load_lds16(Kbase + (size_t)(t0 + kv) * 256 + (((lane & 15) ^ (kv & 7)) << 4),
                 kd + ch * 1024);
      const int dv = ch * 8 + (lane >> 3);
      load_lds16(Vbase + (size_t)dv * (T_ * 2) + (size_t)t0 * 2 +
                     (((lane & 7) ^ (dv & 7)) << 4),
                 vd + ch * 1024);
    }
  };

  STAGE(0, 0);
  __syncthreads();
  int cur = 0;
  for (int tt = 0; tt < nt; ++tt) {
    const int t0 = tt * 64;
    if (tt + 1 < nt) STAGE(tt + 1, cur ^ 1);     // prefetch overlaps compute
    if (t0 <= qbase + 31) {
      const char* kd = smem + cur * 32768;
      const char* vd = kd + 16384;
      f32x16 sA, sB;
#pragma unroll
      for (int r = 0; r < 16; ++r) { sA[r] = 0.f; sB[r] = 0.f; }
      __builtin_amdgcn_s_setprio(1);
#pragma unroll
      for (int t = 0; t < 8; ++t) {
        const int sw = t * 2 + hi;
        bf16x8 ka = *(const bf16x8*)(kd + lq * 256 + ((sw ^ (lq & 7)) << 4));
        bf16x8 kb = *(const bf16x8*)(kd + (lq + 32) * 256 + ((sw ^ (lq & 7)) << 4));
        sA = mfma32(ka, qf[t], sA);
        sB = mfma32(kb, qf[t], sB);
      }
      __builtin_amdgcn_s_setprio(0);
      float p[32];
      float mx = -1e30f;
      const bool anymask = (t0 + 63 > qbase);
#pragma unroll
      for (int r = 0; r < 16; ++r) {
        const int kv = (r & 3) + ((r >> 2) << 3) + hi * 4;
        float vA = sA[r] * SL2E_;
        float vB = sB[r] * SL2E_;
        if (anymask) {
          if (t0 + kv > qrow) vA = -1e30f;
          if (t0 + kv + 32 > qrow) vB = -1e30f;
        }
        p[r] = vA; p[16 + r] = vB;
        mx = fmaxf(mx, fmaxf(vA, vB));
      }
      mx = fmaxf(mx, __shfl_xor(mx, 32));
      // T13 defer-max: rescale only when some lane's max grew past m_r + 8
      if (!__all(mx <= m_r + 8.f)) {
        const float mn = fmaxf(m_r, mx);
        const float al = exp2f(m_r - mn);
        l_r *= al;
#pragma unroll
        for (int d = 0; d < 4; ++d)
#pragma unroll
          for (int r = 0; r < 16; ++r) o[d][r] *= al;
        m_r = mn;
      }
      float sum = 0.f;
#pragma unroll
      for (int j = 0; j < 32; ++j) { p[j] = exp2f(p[j] - m_r); sum += p[j]; }
      sum += __shfl_xor(sum, 32);
      l_r += sum;
      bf16x8 pf[4];
#pragma unroll
      for (int kt = 0; kt < 4; ++kt) {
        const float* pp = p + kt * 8;
        unsigned a0 = cvtpk(pp[0], pp[1]);
        unsigned a1 = cvtpk(pp[2], pp[3]);
        unsigned b0 = cvtpk(pp[4], pp[5]);
        unsigned b1 = cvtpk(pp[6], pp[7]);
        pl32swap(a0, b0);
        pl32swap(a1, b1);
        u32x4 w = {a0, a1, b0, b1};
        pf[kt] = __builtin_bit_cast(bf16x8, w);
      }
      __builtin_amdgcn_s_setprio(1);
#pragma unroll
      for (int dt = 0; dt < 4; ++dt) {
        const int d = dt * 32 + lq;
#pragma unroll
        for (int kt = 0; kt < 4; ++kt) {
          bf16x8 vf = *(const bf16x8*)(vd + d * 128 + (((kt * 2 + hi) ^ (d & 7)) << 4));
          o[dt] = mfma32(vf, pf[kt], o[dt]);
        }
      }
      __builtin_amdgcn_s_setprio(0);
    }
    __syncthreads();
    cur ^= 1;
  }
  const float inv = 1.f / l_r;
  const unsigned short* grow = qkv + (size_t)(b * T_ + qrow) * NQKV_ + h * 256 + 128;
  unsigned short* orow = attnb + (size_t)(b * T_ + qrow) * (NH_ * HD_) + h * HD_;
#pragma unroll
  for (int dt = 0; dt < 4; ++dt)
#pragma unroll
    for (int g = 0; g < 4; ++g) {
      const int d0 = dt * 32 + g * 8 + hi * 4;
      ushort4 gv = *(const ushort4*)(grow + d0);
      ushort4 ov;
      ov.x = f2b(o[dt][g * 4 + 0] * inv / (1.f + __expf(-b2f(gv.x))));
      ov.y = f2b(o[dt][g * 4 + 1] * inv / (1.f + __expf(-b2f(gv.y))));
      ov.z = f2b(o[dt][g * 4 + 2] * inv / (1.f + __expf(-b2f(gv.z))));
      ov.w = f2b(o[dt][g * 4 + 3] * inv / (1.f + __expf(-b2f(gv.w))));
      *(ushort4*)(orow + d0) = ov;
    }
}

// ---------------------------------------------------------------- launch
extern "C" void kernel_launch(void* const* d_in, const int* in_sizes, int n_in,
                              void* d_out, int out_size, void* d_ws, size_t ws_size,
                              hipStream_t stream) {
  (void)in_sizes; (void)n_in; (void)out_size; (void)ws_size;
  const float* x    = (const float*)d_in[0];
  const float* cosT = (const float*)d_in[1];
  const float* sinT = (const float*)d_in[2];
  const float* wq   = (const float*)d_in[3];
  const float* wk   = (const float*)d_in[4];
  const float* wv   = (const float*)d_in[5];
  const float* wo   = (const float*)d_in[6];
  const float* qnw  = (const float*)d_in[7];
  const float* knw  = (const float*)d_in[8];
  // d_in[9] segment_ids (all ones), d_in[10] position_ids (arange) -> pure causal
  float* out = (float*)d_out;
  char* ws = (char*)d_ws;

  constexpr size_t OFF_XB    = 0;                                   // 4096x2048 bf16
  constexpr size_t OFF_WQKVT = OFF_XB    + (size_t)4096 * 2048 * 2; // 5120x2048 bf16
  constexpr size_t OFF_WOT   = OFF_WQKVT + (size_t)5120 * 2048 * 2; // 2048x2048 bf16
  constexpr size_t OFF_QKV   = OFF_WOT   + (size_t)2048 * 2048 * 2; // 4096x5120 bf16
  constexpr size_t OFF_QG    = OFF_QKV   + (size_t)4096 * 5120 * 2; // (B,NH,T,HD) bf16
  constexpr size_t OFF_KG    = OFF_QG    + (size_t)2 * 16 * 2048 * 128 * 2;
  constexpr size_t OFF_VT    = OFF_KG    + (size_t)2 * 4 * 2048 * 128 * 2;
  constexpr size_t OFF_ATTNB = OFF_VT    + (size_t)2 * 4 * 128 * 2048 * 2;

  unsigned short* xb    = (unsigned short*)(ws + OFF_XB);
  unsigned short* wqkvT = (unsigned short*)(ws + OFF_WQKVT);
  unsigned short* woT   = (unsigned short*)(ws + OFF_WOT);
  unsigned short* qkv   = (unsigned short*)(ws + OFF_QKV);
  unsigned short* Qg    = (unsigned short*)(ws + OFF_QG);
  unsigned short* Kg    = (unsigned short*)(ws + OFF_KG);
  unsigned short* Vt    = (unsigned short*)(ws + OFF_VT);
  unsigned short* attnb = (unsigned short*)(ws + OFF_ATTNB);

  const int nX = 4096 * 2048;
  conv_bf16_kernel<<<nX / 4 / 256, 256, 0, stream>>>(x, xb, nX);
  // fused QKV weight transpose (one launch) + wo transpose, vectorized stores
  tconv_qkv_kernel<<<dim3(5120 / 32, 2048 / 32), 256, 0, stream>>>(wq, wk, wv, wqkvT);
  tconv_kernel<<<dim3(2048 / 32, 2048 / 32), 256, 0, stream>>>(wo, woT, 2048, 2048);

  // QKV GEMM (R3-verified): bf16 out; V columns written transposed to Vt directly
  gemm_bt8_kernel<1><<<dim3(5120 / 256, 4096 / 128), 512, 0, stream>>>(
      xb, wqkvT, (void*)qkv, Vt, 2048, 5120);

  postproc_kernel<<<4096, 256, 0, stream>>>(qkv, cosT, sinT, qnw, knw, Qg, Kg);

  attn_kernel<<<512, 256, 0, stream>>>(Qg, Kg, Vt, qkv, attnb);

  // out-proj GEMM: f32 output
  gemm_bt8_kernel<0><<<dim3(2048 / 256, 4096 / 128), 512, 0, stream>>>(
      attnb, woT, (void*)out, nullptr, 2048, 2048);
}

// Round 19
// 262.346 us; speedup vs baseline: 1.0084x; 1.0084x over previous
//
#include <hip/hip_runtime.h>

#define AS1 __attribute__((address_space(1)))
#define AS3 __attribute__((address_space(3)))

typedef __bf16 bf16x8 __attribute__((ext_vector_type(8)));
typedef float f32x4 __attribute__((ext_vector_type(4)));
typedef float f32x16 __attribute__((ext_vector_type(16)));
typedef unsigned short us8 __attribute__((ext_vector_type(8)));
typedef unsigned int u32x4 __attribute__((ext_vector_type(4)));

static constexpr int T_ = 2048;
static constexpr int NH_ = 16;
static constexpr int NKV_ = 4;
static constexpr int HD_ = 128;
static constexpr int NQKV_ = 5120;   // 4096 (q|gate interleaved per head) + 512 k + 512 v
// 1/sqrt(128) * log2(e): softmax computed in exp2 domain
static constexpr float SL2E_ = 0.12751744f;

static __device__ __forceinline__ unsigned short f2b(float f) {
  unsigned u = __builtin_bit_cast(unsigned, f);
  u += 0x7fffu + ((u >> 16) & 1u);
  return (unsigned short)(u >> 16);
}
static __device__ __forceinline__ float b2f(unsigned short h) {
  unsigned u = ((unsigned)h) << 16;
  return __builtin_bit_cast(float, u);
}
static __device__ __forceinline__ void load_lds16(const void* g, void* l) {
  __builtin_amdgcn_global_load_lds((const AS1 unsigned int*)g, (AS3 unsigned int*)l, 16, 0, 0);
}
static __device__ __forceinline__ f32x4 mfma16(bf16x8 a, bf16x8 b, f32x4 c) {
  return __builtin_amdgcn_mfma_f32_16x16x32_bf16(a, b, c, 0, 0, 0);
}
static __device__ __forceinline__ f32x16 mfma32(bf16x8 a, bf16x8 b, f32x16 c) {
  return __builtin_amdgcn_mfma_f32_32x32x16_bf16(a, b, c, 0, 0, 0);
}
static __device__ __forceinline__ unsigned cvtpk(float lo, float hi) {
  unsigned r;
  asm("v_cvt_pk_bf16_f32 %0, %1, %2" : "=v"(r) : "v"(lo), "v"(hi));
  return r;
}
static __device__ __forceinline__ void pl32swap(unsigned& a, unsigned& b) {
  asm("v_permlane32_swap_b32 %0, %1" : "+v"(a), "+v"(b));
}
#define S_BARRIER() asm volatile("s_barrier" ::: "memory")
#define VMCNT(n) asm volatile("s_waitcnt vmcnt(" #n ")" ::: "memory")

// ---------------------------------------------------------------- conversions
__global__ __launch_bounds__(256) void conv_bf16_kernel(
    const float* __restrict__ src, unsigned short* __restrict__ dst, int n) {
  int i = (blockIdx.x * 256 + threadIdx.x) * 4;
  if (i >= n) return;
  float4 v = *(const float4*)(src + i);
  ushort4 o;
  o.x = f2b(v.x); o.y = f2b(v.y); o.z = f2b(v.z); o.w = f2b(v.w);
  *(ushort4*)(dst + i) = o;
}

// transpose-convert with vectorized stores: src f32 (R x C) row-major ->
// dst bf16 rows [roff+c0 .. ) x R. 32x32 tile; loads coalesced f32; each thread
// stores one ushort4 (8B/lane vs 2B/lane scalar).
static __device__ __forceinline__ void tconv_tile(
    const float* __restrict__ src, unsigned short* __restrict__ dst,
    int R, int C, int roff, int c0, int r0) {
  __shared__ float tile[32][33];
  const int tx = threadIdx.x & 31, ty = threadIdx.x >> 5;   // 32 x 8
#pragma unroll
  for (int j = 0; j < 32; j += 8)
    tile[ty + j][tx] = src[(size_t)(r0 + ty + j) * C + c0 + tx];
  __syncthreads();
  const int orow = threadIdx.x >> 3;          // 0..31: output row (= src col)
  const int oc4 = (threadIdx.x & 7) * 4;      // 0..28: first of 4 output cols (= src rows)
  ushort4 o;
  o.x = f2b(tile[oc4 + 0][orow]);
  o.y = f2b(tile[oc4 + 1][orow]);
  o.z = f2b(tile[oc4 + 2][orow]);
  o.w = f2b(tile[oc4 + 3][orow]);
  *(ushort4*)&dst[(size_t)(roff + c0 + orow) * R + r0 + oc4] = o;
}

// fused QKV weight transpose: one launch covers all 5120 output rows.
// global col gc0 selects source: [0,4096) wq, [4096,4608) wk, [4608,5120) wv.
__global__ __launch_bounds__(256) void tconv_qkv_kernel(
    const float* __restrict__ wq, const float* __restrict__ wk,
    const float* __restrict__ wv, unsigned short* __restrict__ dst) {
  const int gc0 = blockIdx.x * 32, r0 = blockIdx.y * 32;
  const float* src;
  int C, c0;
  if (gc0 < 4096)      { src = wq; C = 4096; c0 = gc0; }
  else if (gc0 < 4608) { src = wk; C = 512;  c0 = gc0 - 4096; }
  else                 { src = wv; C = 512;  c0 = gc0 - 4608; }
  // dst row = gc0 + local col; write with roff folded into gc0-c0
  tconv_tile(src, dst, 2048, C, gc0 - c0, c0, r0);
}

__global__ __launch_bounds__(256) void tconv_kernel(
    const float* __restrict__ src, unsigned short* __restrict__ dst, int R, int C) {
  tconv_tile(src, dst, R, C, 0, blockIdx.x * 32, blockIdx.y * 32);
}

// ---------------------------------------------------------------- GEMM (R3-verified structure)
// A (M x K) bf16, Bt (N x K) bf16, C (M x N).  BM=128 BN=256 BK=64, 8 waves (2Mx4N),
// triple-buffered LDS, prefetch distance 2, counted vmcnt(6), XOR slot-swizzle.
// T1 XCD-bijective block swizzle (nwg % 8 == 0): each XCD gets a contiguous chunk of
// the linearized grid -> neighboring tiles share A/B panels in the same L2, cutting
// over-fetch and shortening average load latency at the counted vmcnt wait.
// BF16OUT=1 (QKV gemm): blocks with bcol>=4608 write V transposed straight to Vt.
template <int BF16OUT>
__global__ __launch_bounds__(512, 2) void gemm_bt8_kernel(
    const unsigned short* __restrict__ A, const unsigned short* __restrict__ Bt,
    void* __restrict__ Cv, unsigned short* __restrict__ Vt, int K, int N) {
  __shared__ __align__(16) unsigned short As[3][128 * 64];
  __shared__ __align__(16) unsigned short Bs[3][256 * 64];
  const int tid = threadIdx.x;
  const int wid = tid >> 6, lane = tid & 63;
  const int lq = lane & 15, lg = lane >> 4;
  const int l8 = lane >> 3, s8 = lane & 7;
  const int wr = wid >> 2, wc = wid & 3;          // 2 x 4 wave grid
  const int nwg = gridDim.x * gridDim.y;
  int bid = blockIdx.y * gridDim.x + blockIdx.x;
  bid = (bid & 7) * (nwg >> 3) + (bid >> 3);      // XCD-bijective swizzle
  const int brow = (bid / gridDim.x) * 128, bcol = (bid % gridDim.x) * 256;

  f32x4 acc[4][4];
#pragma unroll
  for (int m = 0; m < 4; ++m)
#pragma unroll
    for (int n = 0; n < 4; ++n) acc[m][n] = (f32x4){0.f, 0.f, 0.f, 0.f};

  auto STAGE_HALF = [&](int t, int b3t, int half) {
    const int k0 = t * 64;
    {
      const int ca = wid + half * 8;
      const int row = ca * 8 + l8;
      load_lds16(A + (size_t)(brow + row) * K + k0 + ((s8 ^ (row & 7)) << 3),
                 &As[b3t][ca << 9]);
    }
#pragma unroll
    for (int j = 0; j < 2; ++j) {
      const int cb = wid + half * 16 + (j << 3);
      const int row = cb * 8 + l8;
      load_lds16(Bt + (size_t)(bcol + row) * K + k0 + ((s8 ^ (row & 7)) << 3),
                 &Bs[b3t][cb << 9]);
    }
  };
  auto PHASE_READS = [&](int b3, int ks, bf16x8* a, bf16x8* bb) {
#pragma unroll
    for (int m = 0; m < 4; ++m) {
      const int r = wr * 64 + m * 16 + lq;
      a[m] = *(const bf16x8*)&As[b3][r * 64 + (((ks * 4 + lg) ^ (r & 7)) << 3)];
    }
#pragma unroll
    for (int n = 0; n < 4; ++n) {
      const int r = wc * 64 + n * 16 + lq;
      bb[n] = *(const bf16x8*)&Bs[b3][r * 64 + (((ks * 4 + lg) ^ (r & 7)) << 3)];
    }
  };
  auto DO_MFMA = [&](bf16x8* a, bf16x8* bb) {
    __builtin_amdgcn_s_setprio(1);
#pragma unroll
    for (int m = 0; m < 4; ++m)
#pragma unroll
      for (int n = 0; n < 4; ++n) acc[m][n] = mfma16(a[m], bb[n], acc[m][n]);
    __builtin_amdgcn_s_setprio(0);
  };

  STAGE_HALF(0, 0, 0); STAGE_HALF(0, 0, 1);
  STAGE_HALF(1, 1, 0); STAGE_HALF(1, 1, 1);
  VMCNT(6);
  S_BARRIER();

  int b3 = 0;
  for (int t = 0; t < 32; ++t) {
    const int b3p2 = b3 < 1 ? b3 + 2 : b3 - 1;
    bf16x8 a[4], bb[4];
    PHASE_READS(b3, 0, a, bb);
    if (t < 30) STAGE_HALF(t + 2, b3p2, 0);
    S_BARRIER();
    __builtin_amdgcn_sched_barrier(0);
    DO_MFMA(a, bb);
    S_BARRIER();
    PHASE_READS(b3, 1, a, bb);
    if (t < 30) STAGE_HALF(t + 2, b3p2, 1);
    if (t < 30) {
      VMCNT(6);
    } else if (t == 30) {
      VMCNT(0);
    }
    S_BARRIER();
    __builtin_amdgcn_sched_barrier(0);
    DO_MFMA(a, bb);
    if (t < 31) S_BARRIER();
    b3 = b3 < 2 ? b3 + 1 : 0;
  }
  if constexpr (BF16OUT) {
    if (bcol >= 4608) {
      // V columns: write transposed to Vt (B,NKV,HD,T), contiguous in t per lane
#pragma unroll
      for (int m = 0; m < 4; ++m) {
        const int R0 = brow + wr * 64 + m * 16 + lg * 4;   // = b*2048 + t0 (t0 % 4 == 0)
        const int bb2 = R0 >> 11, tt0 = R0 & 2047;
#pragma unroll
        for (int n = 0; n < 4; ++n) {
          const int vcol = bcol + wc * 64 + n * 16 + lq - 4608;   // 0..511
          const int vh = vcol >> 7, d = vcol & 127;
          ushort4 v4;
          v4.x = f2b(acc[m][n][0]); v4.y = f2b(acc[m][n][1]);
          v4.z = f2b(acc[m][n][2]); v4.w = f2b(acc[m][n][3]);
          *(ushort4*)&Vt[(size_t)((bb2 * 4 + vh) * 128 + d) * 2048 + tt0] = v4;
        }
      }
      return;
    }
  }
#pragma unroll
  for (int m = 0; m < 4; ++m)
#pragma unroll
    for (int n = 0; n < 4; ++n)
#pragma unroll
      for (int r = 0; r < 4; ++r) {
        const size_t idx =
            (size_t)(brow + wr * 64 + m * 16 + lg * 4 + r) * N + bcol + wc * 64 + n * 16 + lq;
        if constexpr (BF16OUT) {
          ((unsigned short*)Cv)[idx] = f2b(acc[m][n][r]);
        } else {
          ((float*)Cv)[idx] = acc[m][n][r];
        }
      }
}

// ---------------------------------------------------------------- rmsnorm + rope + layout
__global__ __launch_bounds__(256) void postproc_kernel(
    const unsigned short* __restrict__ qkv, const float* __restrict__ cosT,
    const float* __restrict__ sinT, const float* __restrict__ qnw,
    const float* __restrict__ knw, unsigned short* __restrict__ Qg,
    unsigned short* __restrict__ Kg) {
  const int row = blockIdx.x;                 // b*T + t
  const int b = row >> 11, t = row & 2047;
  const unsigned short* src = qkv + (size_t)row * NQKV_;
  const int tid = threadIdx.x;
  const int sub = tid & 15;
  const int i0 = sub * 8;
  const bool lo = sub < 8;

  float cs[8], sn[8];
#pragma unroll
  for (int j = 0; j < 8; ++j) {
    cs[j] = cosT[(size_t)row * HD_ + i0 + j];
    sn[j] = sinT[(size_t)row * HD_ + i0 + j];
  }
  {
    const int h = tid >> 4;
    us8 qv = *(const us8*)(src + h * 256 + i0);
    float q[8], ss = 0.f;
#pragma unroll
    for (int j = 0; j < 8; ++j) { q[j] = b2f(qv[j]); ss += q[j] * q[j]; }
    ss += __shfl_xor(ss, 1); ss += __shfl_xor(ss, 2);
    ss += __shfl_xor(ss, 4); ss += __shfl_xor(ss, 8);
    const float rms = rsqrtf(ss * (1.f / 128.f) + 1e-6f);
    float qn[8];
#pragma unroll
    for (int j = 0; j < 8; ++j) qn[j] = q[j] * rms * qnw[i0 + j];
    float pr[8];
#pragma unroll
    for (int j = 0; j < 8; ++j) pr[j] = __shfl_xor(qn[j], 8);
    us8 ov;
#pragma unroll
    for (int j = 0; j < 8; ++j) ov[j] = f2b(qn[j] * cs[j] + (lo ? -pr[j] : pr[j]) * sn[j]);
    *(us8*)(Qg + ((size_t)(b * NH_ + h) * T_ + t) * HD_ + i0) = ov;
  }
  if (tid < 64) {
    const int kh = tid >> 4;
    us8 kv8 = *(const us8*)(src + 4096 + kh * 128 + i0);
    float k[8], ss = 0.f;
#pragma unroll
    for (int j = 0; j < 8; ++j) { k[j] = b2f(kv8[j]); ss += k[j] * k[j]; }
    ss += __shfl_xor(ss, 1); ss += __shfl_xor(ss, 2);
    ss += __shfl_xor(ss, 4); ss += __shfl_xor(ss, 8);
    const float rms = rsqrtf(ss * (1.f / 128.f) + 1e-6f);
    float kn[8];
#pragma unroll
    for (int j = 0; j < 8; ++j) kn[j] = k[j] * rms * knw[i0 + j];
    float pr[8];
#pragma unroll
    for (int j = 0; j < 8; ++j) pr[j] = __shfl_xor(kn[j], 8);
    us8 ov;
#pragma unroll
    for (int j = 0; j < 8; ++j) ov[j] = f2b(kn[j] * cs[j] + (lo ? -pr[j] : pr[j]) * sn[j]);
    *(us8*)(Kg + ((size_t)(b * NKV_ + kh) * T_ + t) * HD_ + i0) = ov;
  }
}

// ---------------------------------------------------------------- flash attention
// R2-VERIFIED sync structure (passed 14 rounds incl. graph replays). Do NOT convert to
// raw s_barrier + counted vmcnt without a dedicated race screen (R7 diverged).
// T13 defer-max (wave-uniform VALU-only branch, no sync change).
__global__ __launch_bounds__(256, 2) void attn_kernel(
    const unsigned short* __restrict__ Qg, const unsigned short* __restrict__ Kg,
    const unsigned short* __restrict__ Vt, const unsigned short* __restrict__ qkv,
    unsigned short* __restrict__ attnb) {
  __shared__ __align__(16) char smem[65536];  // [2][ K 16KB | V 16KB ]
  const int i = blockIdx.x;
  const int xi = (i >> 3) & 15;                    // q-tile slot within group
  const int grp = (i & 7) + ((i >> 7) << 3);       // 0..31 = h + 16*b
  const int h = grp & 15, b = grp >> 4;
  const int qt = b ? (15 - xi) : xi;               // heavy+light pairing across b
  const int kh = h >> 2;
  const int tid = threadIdx.x, wid = tid >> 6, lane = tid & 63;
  const int lq = lane & 31, hi = lane >> 5;
  const int q0 = qt * 128;
  const int qbase = q0 + wid * 32;                 // wave's 32 q-rows
  const int qrow = qbase + lq;                     // this lane's q-row

  bf16x8 qf[8];
  const unsigned short* qptr = Qg + ((size_t)(b * NH_ + h) * T_ + qrow) * HD_;
#pragma unroll
  for (int t = 0; t < 8; ++t) qf[t] = *(const bf16x8*)(qptr + t * 16 + hi * 8);

  const char* Kbase = (const char*)(Kg + (size_t)(b * NKV_ + kh) * T_ * HD_);
  const char* Vbase = (const char*)(Vt + (size_t)(b * NKV_ + kh) * HD_ * T_);

  f32x16 o[4];
#pragma unroll
  for (int d = 0; d < 4; ++d)
#pragma unroll
    for (int r = 0; r < 16; ++r) o[d][r] = 0.f;
  float m_r = -1e30f, l_r = 0.f;
  const int nt = 2 * qt + 2;

  auto STAGE = [&](int tt, int c) {
    const int t0 = tt * 64;
    char* kd = smem + c * 32768;
    char* vd = kd + 16384;
#pragma unroll
    for (int j = 0; j < 4; ++j) {
      const int ch = j * 4 + wid;
      const int kv = ch * 4 + (lane >> 4);
      load_lds16(Kbase + (size_t)(t0 + kv) * 256 + (((lane & 15) ^ (kv & 7)) << 4),
                 kd + ch * 1024);
      const int dv = ch * 8 + (lane >> 3);
      load_lds16(Vbase + (size_t)dv * (T_ * 2) + (size_t)t0 * 2 +
                     (((lane & 7) ^ (dv & 7)) << 4),
                 vd + ch * 1024);
    }
  };

  STAGE(0, 0);
  __syncthreads();
  int cur = 0;
  for (int tt = 0; tt < nt; ++tt) {
    const int t0 = tt * 64;
    if (tt + 1 < nt) STAGE(tt + 1, cur ^ 1);     // prefetch overlaps compute
    if (t0 <= qbase + 31) {
      const char* kd = smem + cur * 32768;
      const char* vd = kd + 16384;
      f32x16 sA, sB;
#pragma unroll
      for (int r = 0; r < 16; ++r) { sA[r] = 0.f; sB[r] = 0.f; }
      __builtin_amdgcn_s_setprio(1);
#pragma unroll
      for (int t = 0; t < 8; ++t) {
        const int sw = t * 2 + hi;
        bf16x8 ka = *(const bf16x8*)(kd + lq * 256 + ((sw ^ (lq & 7)) << 4));
        bf16x8 kb = *(const bf16x8*)(kd + (lq + 32) * 256 + ((sw ^ (lq & 7)) << 4));
        sA = mfma32(ka, qf[t], sA);
        sB = mfma32(kb, qf[t], sB);
      }
      __builtin_amdgcn_s_setprio(0);
      float p[32];
      float mx = -1e30f;
      const bool anymask = (t0 + 63 > qbase);
#pragma unroll
      for (int r = 0; r < 16; ++r) {
        const int kv = (r & 3) + ((r >> 2) << 3) + hi * 4;
        float vA = sA[r] * SL2E_;
        float vB = sB[r] * SL2E_;
        if (anymask) {
          if (t0 + kv > qrow) vA = -1e30f;
          if (t0 + kv + 32 > qrow) vB = -1e30f;
        }
        p[r] = vA; p[16 + r] = vB;
        mx = fmaxf(mx, fmaxf(vA, vB));
      }
      mx = fmaxf(mx, __shfl_xor(mx, 32));
      // T13 defer-max: rescale only when some lane's max grew past m_r + 8
      if (!__all(mx <= m_r + 8.f)) {
        const float mn = fmaxf(m_r, mx);
        const float al = exp2f(m_r - mn);
        l_r *= al;
#pragma unroll
        for (int d = 0; d < 4; ++d)
#pragma unroll
          for (int r = 0; r < 16; ++r) o[d][r] *= al;
        m_r = mn;
      }
      float sum = 0.f;
#pragma unroll
      for (int j = 0; j < 32; ++j) { p[j] = exp2f(p[j] - m_r); sum += p[j]; }
      sum += __shfl_xor(sum, 32);
      l_r += sum;
      bf16x8 pf[4];
#pragma unroll
      for (int kt = 0; kt < 4; ++kt) {
        const float* pp = p + kt * 8;
        unsigned a0 = cvtpk(pp[0], pp[1]);
        unsigned a1 = cvtpk(pp[2], pp[3]);
        unsigned b0 = cvtpk(pp[4], pp[5]);
        unsigned b1 = cvtpk(pp[6], pp[7]);
        pl32swap(a0, b0);
        pl32swap(a1, b1);
        u32x4 w = {a0, a1, b0, b1};
        pf[kt] = __builtin_bit_cast(bf16x8, w);
      }
      __builtin_amdgcn_s_setprio(1);
#pragma unroll
      for (int dt = 0; dt < 4; ++dt) {
        const int d = dt * 32 + lq;
#pragma unroll
        for (int kt = 0; kt < 4; ++kt) {
          bf16x8 vf = *(const bf16x8*)(vd + d * 128 + (((kt * 2 + hi) ^ (d & 7)) << 4));
          o[dt] = mfma32(vf, pf[kt], o[dt]);
        }
      }
      __builtin_amdgcn_s_setprio(0);
    }
    __syncthreads();
    cur ^= 1;
  }
  const float inv = 1.f / l_r;
  const unsigned short* grow = qkv + (size_t)(b * T_ + qrow) * NQKV_ + h * 256 + 128;
  unsigned short* orow = attnb + (size_t)(b * T_ + qrow) * (NH_ * HD_) + h * HD_;
#pragma unroll
  for (int dt = 0; dt < 4; ++dt)
#pragma unroll
    for (int g = 0; g < 4; ++g) {
      const int d0 = dt * 32 + g * 8 + hi * 4;
      ushort4 gv = *(const ushort4*)(grow + d0);
      ushort4 ov;
      ov.x = f2b(o[dt][g * 4 + 0] * inv / (1.f + __expf(-b2f(gv.x))));
      ov.y = f2b(o[dt][g * 4 + 1] * inv / (1.f + __expf(-b2f(gv.y))));
      ov.z = f2b(o[dt][g * 4 + 2] * inv / (1.f + __expf(-b2f(gv.z))));
      ov.w = f2b(o[dt][g * 4 + 3] * inv / (1.f + __expf(-b2f(gv.w))));
      *(ushort4*)(orow + d0) = ov;
    }
}

// ---------------------------------------------------------------- launch
extern "C" void kernel_launch(void* const* d_in, const int* in_sizes, int n_in,
                              void* d_out, int out_size, void* d_ws, size_t ws_size,
                              hipStream_t stream) {
  (void)in_sizes; (void)n_in; (void)out_size; (void)ws_size;
  const float* x    = (const float*)d_in[0];
  const float* cosT = (const float*)d_in[1];
  const float* sinT = (const float*)d_in[2];
  const float* wq   = (const float*)d_in[3];
  const float* wk   = (const float*)d_in[4];
  const float* wv   = (const float*)d_in[5];
  const float* wo   = (const float*)d_in[6];
  const float* qnw  = (const float*)d_in[7];
  const float* knw  = (const float*)d_in[8];
  // d_in[9] segment_ids (all ones), d_in[10] position_ids (arange) -> pure causal
  float* out = (float*)d_out;
  char* ws = (char*)d_ws;

  constexpr size_t OFF_XB    = 0;                                   // 4096x2048 bf16
  constexpr size_t OFF_WQKVT = OFF_XB    + (size_t)4096 * 2048 * 2; // 5120x2048 bf16
  constexpr size_t OFF_WOT   = OFF_WQKVT + (size_t)5120 * 2048 * 2; // 2048x2048 bf16
  constexpr size_t OFF_QKV   = OFF_WOT   + (size_t)2048 * 2048 * 2; // 4096x5120 bf16
  constexpr size_t OFF_QG    = OFF_QKV   + (size_t)4096 * 5120 * 2; // (B,NH,T,HD) bf16
  constexpr size_t OFF_KG    = OFF_QG    + (size_t)2 * 16 * 2048 * 128 * 2;
  constexpr size_t OFF_VT    = OFF_KG    + (size_t)2 * 4 * 2048 * 128 * 2;
  constexpr size_t OFF_ATTNB = OFF_VT    + (size_t)2 * 4 * 128 * 2048 * 2;

  unsigned short* xb    = (unsigned short*)(ws + OFF_XB);
  unsigned short* wqkvT = (unsigned short*)(ws + OFF_WQKVT);
  unsigned short* woT   = (unsigned short*)(ws + OFF_WOT);
  unsigned short* qkv   = (unsigned short*)(ws + OFF_QKV);
  unsigned short* Qg    = (unsigned short*)(ws + OFF_QG);
  unsigned short* Kg    = (unsigned short*)(ws + OFF_KG);
  unsigned short* Vt    = (unsigned short*)(ws + OFF_VT);
  unsigned short* attnb = (unsigned short*)(ws + OFF_ATTNB);

  const int nX = 4096 * 2048;
  conv_bf16_kernel<<<nX / 4 / 256, 256, 0, stream>>>(x, xb, nX);
  // fused QKV weight transpose (one launch) + wo transpose, vectorized stores
  tconv_qkv_kernel<<<dim3(5120 / 32, 2048 / 32), 256, 0, stream>>>(wq, wk, wv, wqkvT);
  tconv_kernel<<<dim3(2048 / 32, 2048 / 32), 256, 0, stream>>>(wo, woT, 2048, 2048);

  // QKV GEMM (R3-verified + T1 XCD swizzle): bf16 out; V written transposed to Vt
  gemm_bt8_kernel<1><<<dim3(5120 / 256, 4096 / 128), 512, 0, stream>>>(
      xb, wqkvT, (void*)qkv, Vt, 2048, 5120);

  postproc_kernel<<<4096, 256, 0, stream>>>(qkv, cosT, sinT, qnw, knw, Qg, Kg);

  attn_kernel<<<512, 256, 0, stream>>>(Qg, Kg, Vt, qkv, attnb);

  // out-proj GEMM (+ T1 XCD swizzle): f32 output
  gemm_bt8_kernel<0><<<dim3(2048 / 256, 4096 / 128), 512, 0, stream>>>(
      attnb, woT, (void*)out, nullptr, 2048, 2048);
}